// Round 2
// baseline (647.383 us; speedup 1.0000x reference)
//
#include <hip/hip_runtime.h>
#include <stdint.h>

// out[8192,4096] = x[8192,4096] @ (A[4096,16] @ B[16,4096]), ALL FP32.
// Fused low-rank: per block of MB=16 rows, T = x@A (waves own 4 rows each,
// lanes split K, float4 loads, butterfly reduce), T via LDS, out = T@B
// (B frags in regs, float4 stores). ~268 MB HBM traffic -> ~43 us floor.

#define KD 4096   // D_IN
#define ND 4096   // D_OUT
#define NR 16     // rank
#define BLK 256
#define RPW 4     // rows per wave
#define MB 16     // rows per block = 4 waves * RPW

__global__ __launch_bounds__(BLK, 4)
void lora_fused(const float* __restrict__ X,
                const float* __restrict__ A,
                const float* __restrict__ Bm,
                float* __restrict__ O)
{
    __shared__ float t_s[MB][NR];

    const int tid  = threadIdx.x;
    const int wv   = tid >> 6;
    const int lane = tid & 63;
    const size_t m0 = (size_t)blockIdx.x * MB;
    const int row0 = wv * RPW;

    // ---------------- Phase A: T = X @ A ----------------
    float acc[RPW][NR];
    #pragma unroll
    for (int i = 0; i < RPW; ++i)
        #pragma unroll
        for (int r = 0; r < NR; ++r) acc[i][r] = 0.f;

    #pragma unroll 1
    for (int s = 0; s < KD / 256; ++s) {         // 16 steps; lane owns 4 consecutive k
        const int k0 = s * 256 + lane * 4;
        float4 xv[RPW];
        #pragma unroll
        for (int i = 0; i < RPW; ++i)
            xv[i] = *reinterpret_cast<const float4*>(X + (m0 + row0 + i) * KD + k0);

        #pragma unroll
        for (int j = 0; j < 4; ++j) {
            const float4 a0 = *reinterpret_cast<const float4*>(A + (size_t)(k0 + j) * NR + 0);
            const float4 a1 = *reinterpret_cast<const float4*>(A + (size_t)(k0 + j) * NR + 4);
            const float4 a2 = *reinterpret_cast<const float4*>(A + (size_t)(k0 + j) * NR + 8);
            const float4 a3 = *reinterpret_cast<const float4*>(A + (size_t)(k0 + j) * NR + 12);
            const float af[NR] = { a0.x, a0.y, a0.z, a0.w,
                                   a1.x, a1.y, a1.z, a1.w,
                                   a2.x, a2.y, a2.z, a2.w,
                                   a3.x, a3.y, a3.z, a3.w };
            #pragma unroll
            for (int i = 0; i < RPW; ++i) {
                const float xf = (&xv[i].x)[j];   // const idx after full unroll
                #pragma unroll
                for (int r = 0; r < NR; ++r)
                    acc[i][r] = fmaf(xf, af[r], acc[i][r]);
            }
        }
    }

    // Butterfly reduce across the 64-lane wave
    #pragma unroll
    for (int off = 32; off > 0; off >>= 1)
        #pragma unroll
        for (int i = 0; i < RPW; ++i)
            #pragma unroll
            for (int r = 0; r < NR; ++r)
                acc[i][r] += __shfl_xor(acc[i][r], off, 64);

    if (lane == 0) {
        #pragma unroll
        for (int i = 0; i < RPW; ++i)
            #pragma unroll
            for (int r = 0; r < NR; ++r)
                t_s[row0 + i][r] = acc[i][r];
    }
    __syncthreads();

    // ---------------- Phase B: O = T @ B ----------------
    #pragma unroll 1
    for (int p = 0; p < ND / (BLK * 4); ++p) {   // 4 passes, 4 cols/thread
        const int j0 = p * (BLK * 4) + tid * 4;
        float bf[NR][4];
        #pragma unroll
        for (int r = 0; r < NR; ++r) {
            const float4 bv = *reinterpret_cast<const float4*>(Bm + (size_t)r * ND + j0);
            bf[r][0] = bv.x; bf[r][1] = bv.y; bf[r][2] = bv.z; bf[r][3] = bv.w;
        }
        #pragma unroll
        for (int m = 0; m < MB; ++m) {
            const float4 t0 = *reinterpret_cast<const float4*>(&t_s[m][0]);
            const float4 t1 = *reinterpret_cast<const float4*>(&t_s[m][4]);
            const float4 t2 = *reinterpret_cast<const float4*>(&t_s[m][8]);
            const float4 t3 = *reinterpret_cast<const float4*>(&t_s[m][12]);
            const float tr[NR] = { t0.x, t0.y, t0.z, t0.w,
                                   t1.x, t1.y, t1.z, t1.w,
                                   t2.x, t2.y, t2.z, t2.w,
                                   t3.x, t3.y, t3.z, t3.w };
            float o[4] = {0.f, 0.f, 0.f, 0.f};
            #pragma unroll
            for (int r = 0; r < NR; ++r)
                #pragma unroll
                for (int c = 0; c < 4; ++c)
                    o[c] = fmaf(tr[r], bf[r][c], o[c]);

            float4 ov = make_float4(o[0], o[1], o[2], o[3]);
            *reinterpret_cast<float4*>(O + (m0 + m) * ND + j0) = ov;
        }
    }
}

extern "C" void kernel_launch(void* const* d_in, const int* in_sizes, int n_in,
                              void* d_out, int out_size, void* d_ws, size_t ws_size,
                              hipStream_t stream) {
    const float* X  = (const float*)d_in[0];   // [4,2048,4096] fp32
    const float* A  = (const float*)d_in[1];   // [4096,16]     fp32
    const float* Bm = (const float*)d_in[2];   // [16,4096]     fp32
    float* O = (float*)d_out;                  // [4,2048,4096] fp32
    lora_fused<<<8192 / MB, BLK, 0, stream>>>(X, A, Bm, O);
}